// Round 8
// baseline (116.444 us; speedup 1.0000x reference)
//
#include <hip/hip_runtime.h>

#define BN 4
#define CN 256
#define PN 4096
#define QT 64
#define TSTR 264

typedef __attribute__((ext_vector_type(8))) short short8;
typedef __attribute__((ext_vector_type(8))) unsigned short ushort8;
typedef __attribute__((ext_vector_type(4))) float f32x4;
typedef __attribute__((ext_vector_type(2))) unsigned int u32x2;
typedef unsigned int u32;

__device__ __forceinline__ unsigned short f2bf(float f) {
  u32 u = __builtin_bit_cast(u32, f);
  return (unsigned short)((u + 0x7fffu + ((u >> 16) & 1u)) >> 16);
}

__device__ __forceinline__ void async_copy16(const void* g, void* l) {
  __builtin_amdgcn_global_load_lds((const __attribute__((address_space(1))) u32*)g,
                                   (__attribute__((address_space(3))) u32*)l, 16, 0, 0);
}

// ---- fused: per 64-pixel block, compute channel norm + write xnT[b][p][c] bf16
__global__ __launch_bounds__(256) void k_nx(const float* __restrict__ x,
                                            float* __restrict__ mnorm,
                                            unsigned short* __restrict__ xnT) {
  __shared__ unsigned short tl[64 * TSTR];
  __shared__ float red[4][64];
  const int b = blockIdx.y, p0 = blockIdx.x * 64;
  const int tid = threadIdx.x;
  const int tp = tid & 63, cg = tid >> 6;
  const float* xp = x + ((size_t)b * CN + cg * 64) * PN + p0 + tp;
  float v[64];
  float ss = 0.f;
#pragma unroll
  for (int i = 0; i < 64; ++i) {
    v[i] = xp[(size_t)i * PN];
    ss += v[i] * v[i];
  }
  red[cg][tp] = ss;
  __syncthreads();
  float nrm = sqrtf(red[0][tp] + red[1][tp] + red[2][tp] + red[3][tp]);
  float mn = fmaxf(nrm, 1e-8f);
  float rn = 1.f / mn;
  if (cg == 0) mnorm[b * PN + p0 + tp] = mn;
  unsigned int* tl32 = (unsigned int*)tl;
#pragma unroll
  for (int j = 0; j < 32; ++j) {
    unsigned int w = (unsigned int)f2bf(v[2 * j] * rn) |
                     ((unsigned int)f2bf(v[2 * j + 1] * rn) << 16);
    tl32[tp * (TSTR / 2) + cg * 32 + j] = w;
  }
  __syncthreads();
  unsigned short* xd = xnT + ((size_t)b * PN + p0) * CN;
  const int row = tid >> 2, qc = tid & 3;
#pragma unroll
  for (int i = 0; i < 8; ++i) {
    ushort8 o = *(const ushort8*)(tl + row * TSTR + i * 32 + qc * 8);
    *(ushort8*)(xd + (size_t)row * CN + i * 32 + qc * 8) = o;
  }
}

// ---- gxv[b][c][q] = bf16( (W @ xn)[c][q] * mnorm[q] + bias[c] )
__global__ void k_gx(const float* __restrict__ Wm, const float* __restrict__ bias,
                     const unsigned short* __restrict__ xnT, const float* __restrict__ mnorm,
                     unsigned short* __restrict__ gxv) {
  int b = blockIdx.z;
  int m0 = blockIdx.y * 64;
  int q0 = blockIdx.x * 64;
  int tid = threadIdx.x;
  int wave = tid >> 6, lane = tid & 63;
  int lr = lane & 15, g = lane >> 4;

  short8 af[8];
  {
    const float* wr = Wm + (size_t)(m0 + wave * 16 + lr) * CN;
#pragma unroll
    for (int k = 0; k < 8; ++k) {
      const float* ap = wr + k * 32 + g * 8;
      short8 a;
#pragma unroll
      for (int j = 0; j < 8; ++j) a[j] = (short)f2bf(ap[j]);
      af[k] = a;
    }
  }
  f32x4 acc[4];
#pragma unroll
  for (int n = 0; n < 4; ++n) acc[n] = (f32x4){0.f, 0.f, 0.f, 0.f};

  const unsigned short* xb = xnT + (size_t)b * PN * CN;
#pragma unroll
  for (int n = 0; n < 4; ++n) {
    const unsigned short* bp = xb + (size_t)(q0 + n * 16 + lr) * CN + g * 8;
#pragma unroll
    for (int k = 0; k < 8; ++k) {
      short8 bf = *(const short8*)(bp + k * 32);
      acc[n] = __builtin_amdgcn_mfma_f32_16x16x32_bf16(af[k], bf, acc[n], 0, 0, 0);
    }
  }
#pragma unroll
  for (int n = 0; n < 4; ++n) {
    int q = q0 + n * 16 + lr;
    float mn = mnorm[b * PN + q];
#pragma unroll
    for (int i = 0; i < 4; ++i) {
      int c = m0 + wave * 16 + g * 4 + i;
      float v = acc[n][i] * mn + bias[c];
      gxv[((size_t)b * CN + c) * PN + q] = f2bf(v);
    }
  }
}

// ---- fused attention: 8-wave WG, M=32 rows/wave, QT=64, 160KB LDS.
// Fragment-major LDS (frag = 1024B, lane*16 linear) -> conflict-free b128.
// 8-phase schedule per tile: P0-P3 QKT (one nt each), P4-P7 PV (kk,half).
// Counted vmcnt(4) at P0 (K ready) / P4 (V ready); K(t+1)@P2, V(t+1)@P5.
extern __shared__ char smem[];

__global__ __launch_bounds__(512, 2) void k_attn(const unsigned short* __restrict__ xnT,
                                                 const unsigned short* __restrict__ gxv,
                                                 float* __restrict__ d0, float* __restrict__ d1,
                                                 float* __restrict__ d2, float* __restrict__ d3,
                                                 int lq, int ntiles) {
  const int fid = blockIdx.x;
  const int b = fid & 3;
  const int qs = (fid >> 2) & ((1 << lq) - 1);
  const int pblk = fid >> (2 + lq);
  const int tid = threadIdx.x;
  const int wave = tid >> 6, lane = tid & 63, lr = lane & 15, g = lane >> 4;
  const int qbase = qs * (PN >> lq);
  const int p0 = pblk * 256 + wave * 32;
  float* dst = (qs == 0) ? d0 : (qs == 1) ? d1 : (qs == 2) ? d2 : d3;

  const char* xbc = (const char*)xnT + (size_t)b * PN * 512;
  const char* vbc = (const char*)gxv + (size_t)b * CN * PN * 2;

  // per-lane DMA source constants (fragment-major gather; dest is linear ldst)
  const int kofs = (lane & 15) * 512 + (lane >> 4) * 16 + wave * 64;
  const int vofs = wave * 131072 + (lane & 15) * 8192 + (lane >> 4) * 16;
  const int ldst = tid * 16;
  const int lane16 = lane * 16;
  // S write base: frag-linear scatter for D[q][p] of swapped QK^T
  const int swb = lr * 16 + (g >> 1) * 256 + (g & 1) * 8;

  auto issue_K = [&](int t) {
    char* kb = smem + (t & 1) * 65536;
    const char* kg = xbc + (size_t)(qbase + t * QT) * 512 + kofs;
#pragma unroll
    for (int j = 0; j < 4; ++j) async_copy16(kg + j * 8192, kb + ldst + j * 8192);
  };
  auto issue_V = [&](int t) {
    char* vb = smem + (t & 1) * 65536 + 32768;
    const char* vg = vbc + (size_t)(qbase + t * QT) * 2 + vofs;
    async_copy16(vg, vb + ldst);
    async_copy16(vg + 1048576, vb + ldst + 8192);
    async_copy16(vg + 64, vb + ldst + 16384);
    async_copy16(vg + 1048576 + 64, vb + ldst + 24576);
  };

  // start DMA before the Q hoist so it overlaps
  issue_K(0);
  issue_V(0);

  // hoist Q fragments (32 p-rows x 256 ch); layout doubles as B-operand (col=lr=p)
  short8 qf[2][8];
#pragma unroll
  for (int mt = 0; mt < 2; ++mt) {
    const char* qp = xbc + (size_t)(p0 + mt * 16 + lr) * 512 + g * 16;
#pragma unroll
    for (int k = 0; k < 8; ++k) qf[mt][k] = *(const short8*)(qp + k * 64);
  }

  f32x4 yacc[2][16];
#pragma unroll
  for (int mt = 0; mt < 2; ++mt)
#pragma unroll
    for (int n = 0; n < 16; ++n) yacc[mt][n] = (f32x4){0.f, 0.f, 0.f, 0.f};

  char* Sme = smem + 131072 + wave * 4096;
  char* Sw = Sme + swb;

  for (int t = 0; t < ntiles; ++t) {
    const char* kb = smem + (t & 1) * 65536;
    const char* vb = kb + 32768;

    // ---- P0..P3: QKT phases, one nt each (8 K-frag reads, 16 MFMA, pack S)
#pragma unroll
    for (int nt = 0; nt < 4; ++nt) {
      if (nt == 0) {
        asm volatile("s_waitcnt vmcnt(4)" ::: "memory");  // K(t) ready (V(t) in flight)
        __builtin_amdgcn_s_barrier();                     // all waves' K DMA visible
      }
      short8 kf[8];
#pragma unroll
      for (int k = 0; k < 8; ++k)
        kf[k] = *(const short8*)(kb + (nt * 8 + k) * 1024 + lane16);
      if (nt == 2 && t + 1 < ntiles) issue_K(t + 1);
      __builtin_amdgcn_s_barrier();  // phase lockstep
      f32x4 s0 = (f32x4){0.f, 0.f, 0.f, 0.f}, s1 = (f32x4){0.f, 0.f, 0.f, 0.f};
      __builtin_amdgcn_s_setprio(1);
#pragma unroll
      for (int k = 0; k < 8; ++k) {
        s0 = __builtin_amdgcn_mfma_f32_16x16x32_bf16(kf[k], qf[0][k], s0, 0, 0, 0);
        s1 = __builtin_amdgcn_mfma_f32_16x16x32_bf16(kf[k], qf[1][k], s1, 0, 0, 0);
      }
      __builtin_amdgcn_s_setprio(0);
      // relu^2 -> packed bf16 -> frag-linear S for this nt (both mt)
      {
        float a0 = fmaxf(s0[0], 0.f); a0 *= a0;
        float a1 = fmaxf(s0[1], 0.f); a1 *= a1;
        float a2 = fmaxf(s0[2], 0.f); a2 *= a2;
        float a3 = fmaxf(s0[3], 0.f); a3 *= a3;
        u32x2 w;
        asm("v_cvt_pk_bf16_f32 %0, %1, %2" : "=v"(w[0]) : "v"(a0), "v"(a1));
        asm("v_cvt_pk_bf16_f32 %0, %1, %2" : "=v"(w[1]) : "v"(a2), "v"(a3));
        *(u32x2*)(Sw + (nt >> 1) * 1024 + (nt & 1) * 512) = w;
        float b0 = fmaxf(s1[0], 0.f); b0 *= b0;
        float b1 = fmaxf(s1[1], 0.f); b1 *= b1;
        float b2 = fmaxf(s1[2], 0.f); b2 *= b2;
        float b3 = fmaxf(s1[3], 0.f); b3 *= b3;
        u32x2 w2;
        asm("v_cvt_pk_bf16_f32 %0, %1, %2" : "=v"(w2[0]) : "v"(b0), "v"(b1));
        asm("v_cvt_pk_bf16_f32 %0, %1, %2" : "=v"(w2[1]) : "v"(b2), "v"(b3));
        *(u32x2*)(Sw + 2048 + (nt >> 1) * 1024 + (nt & 1) * 512) = w2;
      }
    }

    // ---- P4..P7: PV phases (kk = q-half, hf = n2-half); 8 V-frag reads, 16 MFMA
    short8 pa0, pa1;
#pragma unroll
    for (int ph = 0; ph < 4; ++ph) {
      const int kk = ph >> 1, hf = ph & 1;
      if (ph == 0) {
        if (t + 1 < ntiles) {
          asm volatile("s_waitcnt vmcnt(4)" ::: "memory");  // V(t) ready (K(t+1) in flight)
        } else {
          asm volatile("s_waitcnt vmcnt(0)" ::: "memory");
        }
        __builtin_amdgcn_s_barrier();  // all waves' V DMA visible
      }
      if (hf == 0) {
        pa0 = *(const short8*)(Sme + kk * 1024 + lane16);
        pa1 = *(const short8*)(Sme + 2048 + kk * 1024 + lane16);
      }
      short8 vf[8];
#pragma unroll
      for (int j = 0; j < 8; ++j)
        vf[j] = *(const short8*)(vb + (kk * 16 + hf * 8 + j) * 1024 + lane16);
      if (ph == 2 && t + 1 < ntiles) issue_V(t + 1);
      __builtin_amdgcn_s_barrier();  // phase lockstep
      __builtin_amdgcn_s_setprio(1);
#pragma unroll
      for (int j = 0; j < 8; ++j) {
        const int n2 = hf * 8 + j;
        yacc[0][n2] = __builtin_amdgcn_mfma_f32_16x16x32_bf16(pa0, vf[j], yacc[0][n2], 0, 0, 0);
        yacc[1][n2] = __builtin_amdgcn_mfma_f32_16x16x32_bf16(pa1, vf[j], yacc[1][n2], 0, 0, 0);
      }
      __builtin_amdgcn_s_setprio(0);
    }
  }
  __builtin_amdgcn_s_barrier();

  // ---- epilogue: per-wave LDS transpose (16KB region each) for coalesced [c][p] stores
  // yacc[mt][n2][i] = y[p = p0 + mt*16 + g*4+i][c = n2*16 + lr]
  float* yl = (float*)(smem + wave * 16384);
  const int row8 = lane >> 3, p4 = (lane & 7) << 2;
#pragma unroll
  for (int cc = 0; cc < 4; ++cc) {
#pragma unroll
    for (int nn = 0; nn < 4; ++nn)
#pragma unroll
      for (int mt = 0; mt < 2; ++mt)
#pragma unroll
        for (int i = 0; i < 4; ++i)
          yl[(nn * 16 + lr) * 33 + mt * 16 + g * 4 + i] = yacc[mt][cc * 4 + nn][i];
#pragma unroll
    for (int r2 = 0; r2 < 8; ++r2) {
      int c = r2 * 8 + row8;
      float4 v = *(const float4*)(yl + c * 33 + p4);
      *(float4*)(dst + ((size_t)b * CN + cc * 64 + c) * PN + p0 + p4) = v;
    }
  }
}

// ---- final reduction: out += sum of partials
__global__ void k_add(float* __restrict__ o, const float* __restrict__ a,
                      const float* __restrict__ bb, const float* __restrict__ c,
                      int np, int n4) {
  int i = blockIdx.x * blockDim.x + threadIdx.x;
  int stride = gridDim.x * blockDim.x;
  float4* o4 = (float4*)o;
  const float4* a4 = (const float4*)a;
  const float4* b4 = (const float4*)bb;
  const float4* c4 = (const float4*)c;
  for (; i < n4; i += stride) {
    float4 r = o4[i];
    float4 va = a4[i];
    r.x += va.x; r.y += va.y; r.z += va.z; r.w += va.w;
    if (np > 1) {
      float4 vb = b4[i];
      r.x += vb.x; r.y += vb.y; r.z += vb.z; r.w += vb.w;
      float4 vc = c4[i];
      r.x += vc.x; r.y += vc.y; r.z += vc.z; r.w += vc.w;
    }
    o4[i] = r;
  }
}

extern "C" void kernel_launch(void* const* d_in, const int* in_sizes, int n_in,
                              void* d_out, int out_size, void* d_ws, size_t ws_size,
                              hipStream_t stream) {
  const float* x = (const float*)d_in[0];
  const float* Wm = (const float*)d_in[1];
  const float* bias = (const float*)d_in[2];
  float* out = (float*)d_out;

  char* ws = (char*)d_ws;
  unsigned short* xnT = (unsigned short*)ws;                        // 8 MB  [B][P][C] bf16
  unsigned short* gxv = (unsigned short*)(ws + (size_t)8388608);    // 8 MB  [B][C][P] bf16
  float* mnorm = (float*)(ws + (size_t)16777216);                   // 64 KB [B][P] f32
  float* yp0 = (float*)(ws + (size_t)16842752);                     // 16 MB partials x3
  float* yp1 = yp0 + 4194304;
  float* yp2 = yp1 + 4194304;
  const size_t need4 = 16842752ULL + 3ULL * 16777216ULL;

  hipFuncSetAttribute(reinterpret_cast<const void*>(k_attn),
                      hipFuncAttributeMaxDynamicSharedMemorySize, 163840);

  k_nx<<<dim3(PN / 64, BN), 256, 0, stream>>>(x, mnorm, xnT);
  k_gx<<<dim3(PN / 64, CN / 64, BN), 256, 0, stream>>>(Wm, bias, xnT, mnorm, gxv);
  if (ws_size >= need4) {
    k_attn<<<dim3(256), 512, 163840, stream>>>(xnT, gxv, out, yp0, yp1, yp2, 2, (PN / 4) / QT);
    k_add<<<dim3(1024), 256, 0, stream>>>(out, yp0, yp1, yp2, 3, BN * CN * PN / 4);
  } else {
    k_attn<<<dim3(128), 512, 163840, stream>>>(xnT, gxv, out, yp0, yp0, yp0, 1, (PN / 2) / QT);
    k_add<<<dim3(1024), 256, 0, stream>>>(out, yp0, yp0, yp0, 1, BN * CN * PN / 4);
  }
}

// Round 9
// 101.108 us; speedup vs baseline: 1.1517x; 1.1517x over previous
//
#include <hip/hip_runtime.h>

#define BN 4
#define CN 256
#define PN 4096
#define QT 64
#define TSTR 264

typedef __attribute__((ext_vector_type(8))) short short8;
typedef __attribute__((ext_vector_type(8))) unsigned short ushort8;
typedef __attribute__((ext_vector_type(4))) float f32x4;
typedef __attribute__((ext_vector_type(4))) unsigned int u32x4;
typedef unsigned int u32;

__device__ __forceinline__ unsigned short f2bf(float f) {
  u32 u = __builtin_bit_cast(u32, f);
  return (unsigned short)((u + 0x7fffu + ((u >> 16) & 1u)) >> 16);
}

__device__ __forceinline__ void async_copy16(const void* g, void* l) {
  __builtin_amdgcn_global_load_lds((const __attribute__((address_space(1))) u32*)g,
                                   (__attribute__((address_space(3))) u32*)l, 16, 0, 0);
}

// Frag-major layout (per batch, per 64-q block = 32 KB = 32 frags of 1024B):
//   frag F = nt*8 + kc  (nt = q-sub-block of 16, kc = 32-ch chunk)
//   byte  = F*1024 + (g*16 + lr)*16 + j*2  <->  xn[q = qb*64 + nt*16 + lr][ch = kc*32 + g*8 + j]
// V layout same frag shape but PERMUTED q: frag f = kk*16 + n2 holds
//   byte = f*1024 + (g*16 + lr)*16 + j*2  <->  V[q = kk*32 + perm(g*8+j)][c = n2*16 + lr]
//   perm(k): q32 bits (q4..q0) = (k2, k4, k3, k1, k0)  -- matches cvt_pk'd S word order.

// ---- k_nx: channel norms + xnK (frag-major bf16)
__global__ __launch_bounds__(256) void k_nx(const float* __restrict__ x,
                                            float* __restrict__ mnorm,
                                            unsigned short* __restrict__ xnK) {
  __shared__ unsigned short tl[64 * TSTR];
  __shared__ float red[4][64];
  const int b = blockIdx.y, qb = blockIdx.x, p0 = qb * 64;
  const int tid = threadIdx.x;
  const int tp = tid & 63, cg = tid >> 6;
  const float* xp = x + ((size_t)b * CN + cg * 64) * PN + p0 + tp;
  float v[64];
  float ss = 0.f;
#pragma unroll
  for (int i = 0; i < 64; ++i) {
    v[i] = xp[(size_t)i * PN];
    ss += v[i] * v[i];
  }
  red[cg][tp] = ss;
  __syncthreads();
  float nrm = sqrtf(red[0][tp] + red[1][tp] + red[2][tp] + red[3][tp]);
  float mn = fmaxf(nrm, 1e-8f);
  float rn = 1.f / mn;
  if (cg == 0) mnorm[b * PN + p0 + tp] = mn;
  unsigned int* tl32 = (unsigned int*)tl;
#pragma unroll
  for (int j = 0; j < 32; ++j) {
    unsigned int w = (unsigned int)f2bf(v[2 * j] * rn) |
                     ((unsigned int)f2bf(v[2 * j + 1] * rn) << 16);
    tl32[tp * (TSTR / 2) + cg * 32 + j] = w;
  }
  __syncthreads();
  // frag-major store: linear 16B chunks; chunk idx -> (F, lane'')
  char* dstb = (char*)xnK + (size_t)b * (PN * CN * 2) + (size_t)qb * 32768;
#pragma unroll
  for (int m = 0; m < 8; ++m) {
    int idx = m * 256 + tid;
    int F = idx >> 6, ln = idx & 63;
    int pl = (F >> 3) * 16 + (ln & 15);
    int ch = (F & 7) * 32 + (ln >> 4) * 8;
    ushort8 o = *(const ushort8*)(tl + pl * TSTR + ch);
    *(ushort8*)(dstb + (size_t)idx * 16) = o;
  }
}

// ---- k_gx: gxF[b][qb][frag-major, q-permuted] = bf16((W@xn)*mnorm + bias)
__global__ void k_gx(const float* __restrict__ Wm, const float* __restrict__ bias,
                     const unsigned short* __restrict__ xnK, const float* __restrict__ mnorm,
                     unsigned short* __restrict__ gxF) {
  const int b = blockIdx.z;
  const int m0 = blockIdx.y * 64;
  const int qb = blockIdx.x, q0 = qb * 64;
  const int tid = threadIdx.x;
  const int wave = tid >> 6, lane = tid & 63;
  const int lr = lane & 15, g = lane >> 4;

  short8 af[8];
  {
    const float* wr = Wm + (size_t)(m0 + wave * 16 + lr) * CN;
#pragma unroll
    for (int k = 0; k < 8; ++k) {
      const float* ap = wr + k * 32 + g * 8;
      short8 a;
#pragma unroll
      for (int j = 0; j < 8; ++j) a[j] = (short)f2bf(ap[j]);
      af[k] = a;
    }
  }
  f32x4 acc[4];
#pragma unroll
  for (int n = 0; n < 4; ++n) acc[n] = (f32x4){0.f, 0.f, 0.f, 0.f};

  const char* xb = (const char*)xnK + (size_t)b * (PN * CN * 2) + (size_t)qb * 32768;
#pragma unroll
  for (int n = 0; n < 4; ++n)
#pragma unroll
    for (int k = 0; k < 8; ++k) {
      short8 bf = *(const short8*)(xb + ((n * 8 + k) << 10) + ((g * 16 + lr) << 4));
      acc[n] = __builtin_amdgcn_mfma_f32_16x16x32_bf16(af[k], bf, acc[n], 0, 0, 0);
    }
  // scatter into permuted V-frag layout
  char* vbb = (char*)gxF + (size_t)b * (PN * CN * 2) + (size_t)qb * 32768;
#pragma unroll
  for (int n = 0; n < 4; ++n) {
    int q = q0 + n * 16 + lr;
    float mn = mnorm[b * PN + q];
    int kk = n >> 1;
    int q32 = (n & 1) * 16 + lr;
    int gp = (q32 >> 2) & 3;
    int j = ((q32 >> 4) & 1) * 4 + (q32 & 3);
#pragma unroll
    for (int i = 0; i < 4; ++i) {
      int c = m0 + wave * 16 + g * 4 + i;
      float v = acc[n][i] * mn + bias[c];
      *(unsigned short*)(vbb + ((kk * 16 + (c >> 4)) << 10) + (gp << 8) + ((c & 15) << 4) + (j << 1)) = f2bf(v);
    }
  }
}

// ---- fused attention: 8-wave WG, M=32 rows/wave, QT=64, 128KB LDS dbuf.
// Linear DMA both sides; S lives entirely in registers (q-permuted pack).
extern __shared__ char smem[];

__global__ __launch_bounds__(512, 2) void k_attn(const unsigned short* __restrict__ xnK,
                                                 const unsigned short* __restrict__ gxF,
                                                 float* __restrict__ d0, float* __restrict__ d1,
                                                 float* __restrict__ d2, float* __restrict__ d3,
                                                 int lq, int ntiles) {
  const int fid = blockIdx.x;
  const int b = fid & 3;
  const int qs = (fid >> 2) & ((1 << lq) - 1);
  const int pblk = fid >> (2 + lq);
  const int tid = threadIdx.x;
  const int wave = tid >> 6, lane = tid & 63, lr = lane & 15, g = lane >> 4;
  const int qb0 = (qs * (PN >> lq)) >> 6;
  const int p0 = pblk * 256 + wave * 32;
  float* dst = (qs == 0) ? d0 : (qs == 1) ? d1 : (qs == 2) ? d2 : d3;

  const char* xb = (const char*)xnK + (size_t)b * (PN * CN * 2);
  const char* vg = (const char*)gxF + (size_t)b * (PN * CN * 2);
  const char* kq = xb + (size_t)qb0 * 32768;
  const char* vq = vg + (size_t)qb0 * 32768;
  const int ldst = tid * 16;
  const int lane16 = lane * 16;

  auto issue_K = [&](int t) {
    char* kb = smem + (t & 1) * 65536;
    const char* s = kq + (size_t)t * 32768 + ldst;
#pragma unroll
    for (int j = 0; j < 4; ++j) async_copy16(s + j * 8192, kb + ldst + j * 8192);
  };
  auto issue_V = [&](int t) {
    char* vb = smem + (t & 1) * 65536 + 32768;
    const char* s = vq + (size_t)t * 32768 + ldst;
#pragma unroll
    for (int j = 0; j < 4; ++j) async_copy16(s + j * 8192, vb + ldst + j * 8192);
  };

  issue_K(0);
  issue_V(0);

  // Q hoist from frag-major xnK: B-operand fragments for the wave's 32 p-rows
  short8 qf[2][8];
  {
    const char* qpb = xb + (size_t)(pblk * 4 + (wave >> 1)) * 32768;
#pragma unroll
    for (int mt = 0; mt < 2; ++mt) {
      int ntp = (wave & 1) * 2 + mt;
#pragma unroll
      for (int k = 0; k < 8; ++k)
        qf[mt][k] = *(const short8*)(qpb + ((ntp * 8 + k) << 10) + ((g * 16 + lr) << 4));
    }
  }

  f32x4 yacc[2][16];
#pragma unroll
  for (int mt = 0; mt < 2; ++mt)
#pragma unroll
    for (int n = 0; n < 16; ++n) yacc[mt][n] = (f32x4){0.f, 0.f, 0.f, 0.f};

  for (int t = 0; t < ntiles; ++t) {
    const char* kb = smem + (t & 1) * 65536;
    const char* vb = kb + 32768;

    asm volatile("s_waitcnt vmcnt(4)" ::: "memory");  // K(t) ready (V(t) in flight)
    __builtin_amdgcn_s_barrier();
    if (t + 1 < ntiles) { issue_K(t + 1); issue_V(t + 1); }

    // QKT (swapped: D[q][p] = mfma(K, Q)) + in-register S pack (q-permuted)
    u32 pa[2][2][4];  // [mt][kk][word jw = (nt&1)*2 + h]
#pragma unroll
    for (int nh = 0; nh < 2; ++nh) {
      f32x4 sacc[2][2];
#pragma unroll
      for (int n0 = 0; n0 < 2; ++n0)
#pragma unroll
        for (int mt = 0; mt < 2; ++mt) sacc[n0][mt] = (f32x4){0.f, 0.f, 0.f, 0.f};
      __builtin_amdgcn_s_setprio(1);
#pragma unroll
      for (int k = 0; k < 8; ++k) {
        short8 kf0 = *(const short8*)(kb + ((2 * nh) * 8 + k) * 1024 + lane16);
        short8 kf1 = *(const short8*)(kb + ((2 * nh + 1) * 8 + k) * 1024 + lane16);
        sacc[0][0] = __builtin_amdgcn_mfma_f32_16x16x32_bf16(kf0, qf[0][k], sacc[0][0], 0, 0, 0);
        sacc[0][1] = __builtin_amdgcn_mfma_f32_16x16x32_bf16(kf0, qf[1][k], sacc[0][1], 0, 0, 0);
        sacc[1][0] = __builtin_amdgcn_mfma_f32_16x16x32_bf16(kf1, qf[0][k], sacc[1][0], 0, 0, 0);
        sacc[1][1] = __builtin_amdgcn_mfma_f32_16x16x32_bf16(kf1, qf[1][k], sacc[1][1], 0, 0, 0);
      }
      __builtin_amdgcn_s_setprio(0);
#pragma unroll
      for (int mt = 0; mt < 2; ++mt)
#pragma unroll
        for (int n0 = 0; n0 < 2; ++n0)
#pragma unroll
          for (int h = 0; h < 2; ++h) {
            float a0 = fmaxf(sacc[n0][mt][2 * h], 0.f);
            a0 *= a0;
            float a1 = fmaxf(sacc[n0][mt][2 * h + 1], 0.f);
            a1 *= a1;
            u32 w;
            asm("v_cvt_pk_bf16_f32 %0, %1, %2" : "=v"(w) : "v"(a0), "v"(a1));
            pa[mt][nh][n0 * 2 + h] = w;
          }
    }

    if (t + 1 < ntiles) {
      asm volatile("s_waitcnt vmcnt(8)" ::: "memory");  // V(t) ready (t+1 in flight)
    } else {
      asm volatile("s_waitcnt vmcnt(0)" ::: "memory");
    }
    __builtin_amdgcn_s_barrier();

    // PV: Y[32p][256c] += S @ V (both sides share the same q-permutation)
#pragma unroll
    for (int kk = 0; kk < 2; ++kk) {
      u32x4 w0 = {pa[0][kk][0], pa[0][kk][1], pa[0][kk][2], pa[0][kk][3]};
      u32x4 w1 = {pa[1][kk][0], pa[1][kk][1], pa[1][kk][2], pa[1][kk][3]};
      short8 a0 = __builtin_bit_cast(short8, w0);
      short8 a1 = __builtin_bit_cast(short8, w1);
      __builtin_amdgcn_s_setprio(1);
#pragma unroll
      for (int n2 = 0; n2 < 16; ++n2) {
        short8 vf = *(const short8*)(vb + (kk * 16 + n2) * 1024 + lane16);
        yacc[0][n2] = __builtin_amdgcn_mfma_f32_16x16x32_bf16(a0, vf, yacc[0][n2], 0, 0, 0);
        yacc[1][n2] = __builtin_amdgcn_mfma_f32_16x16x32_bf16(a1, vf, yacc[1][n2], 0, 0, 0);
      }
      __builtin_amdgcn_s_setprio(0);
    }
  }
  __builtin_amdgcn_s_barrier();

  // ---- epilogue: per-wave LDS transpose (16KB each) for coalesced [c][p] stores
  // yacc[mt][n2][i] = y[p = p0 + mt*16 + g*4+i][c = n2*16 + lr]
  float* yl = (float*)(smem + wave * 16384);
  const int row8 = lane >> 3, p4 = (lane & 7) << 2;
#pragma unroll
  for (int cc = 0; cc < 4; ++cc) {
#pragma unroll
    for (int nn = 0; nn < 4; ++nn)
#pragma unroll
      for (int mt = 0; mt < 2; ++mt)
#pragma unroll
        for (int i = 0; i < 4; ++i)
          yl[(nn * 16 + lr) * 33 + mt * 16 + g * 4 + i] = yacc[mt][cc * 4 + nn][i];
#pragma unroll
    for (int r2 = 0; r2 < 8; ++r2) {
      int c = r2 * 8 + row8;
      float4 v = *(const float4*)(yl + c * 33 + p4);
      *(float4*)(dst + ((size_t)b * CN + cc * 64 + c) * PN + p0 + p4) = v;
    }
  }
}

// ---- final reduction: out += sum of partials
__global__ void k_add(float* __restrict__ o, const float* __restrict__ a,
                      const float* __restrict__ bb, const float* __restrict__ c,
                      int np, int n4) {
  int i = blockIdx.x * blockDim.x + threadIdx.x;
  int stride = gridDim.x * blockDim.x;
  float4* o4 = (float4*)o;
  const float4* a4 = (const float4*)a;
  const float4* b4 = (const float4*)bb;
  const float4* c4 = (const float4*)c;
  for (; i < n4; i += stride) {
    float4 r = o4[i];
    float4 va = a4[i];
    r.x += va.x; r.y += va.y; r.z += va.z; r.w += va.w;
    if (np > 1) {
      float4 vb = b4[i];
      r.x += vb.x; r.y += vb.y; r.z += vb.z; r.w += vb.w;
      float4 vc = c4[i];
      r.x += vc.x; r.y += vc.y; r.z += vc.z; r.w += vc.w;
    }
    o4[i] = r;
  }
}

extern "C" void kernel_launch(void* const* d_in, const int* in_sizes, int n_in,
                              void* d_out, int out_size, void* d_ws, size_t ws_size,
                              hipStream_t stream) {
  const float* x = (const float*)d_in[0];
  const float* Wm = (const float*)d_in[1];
  const float* bias = (const float*)d_in[2];
  float* out = (float*)d_out;

  char* ws = (char*)d_ws;
  unsigned short* xnK = (unsigned short*)ws;                        // 8 MB  frag-major xn
  unsigned short* gxF = (unsigned short*)(ws + (size_t)8388608);    // 8 MB  frag-major permuted V
  float* mnorm = (float*)(ws + (size_t)16777216);                   // 64 KB [B][P] f32
  float* yp0 = (float*)(ws + (size_t)16842752);                     // 16 MB partials x3
  float* yp1 = yp0 + 4194304;
  float* yp2 = yp1 + 4194304;
  const size_t need4 = 16842752ULL + 3ULL * 16777216ULL;

  hipFuncSetAttribute(reinterpret_cast<const void*>(k_attn),
                      hipFuncAttributeMaxDynamicSharedMemorySize, 131072);

  k_nx<<<dim3(PN / 64, BN), 256, 0, stream>>>(x, mnorm, xnK);
  k_gx<<<dim3(PN / 64, CN / 64, BN), 256, 0, stream>>>(Wm, bias, xnK, mnorm, gxF);
  if (ws_size >= need4) {
    k_attn<<<dim3(256), 512, 131072, stream>>>(xnK, gxF, out, yp0, yp1, yp2, 2, (PN / 4) / QT);
    k_add<<<dim3(1024), 256, 0, stream>>>(out, yp0, yp1, yp2, 3, BN * CN * PN / 4);
  } else {
    k_attn<<<dim3(128), 512, 131072, stream>>>(xnK, gxF, out, yp0, yp0, yp0, 1, (PN / 2) / QT);
    k_add<<<dim3(1024), 256, 0, stream>>>(out, yp0, yp0, yp0, 1, BN * CN * PN / 4);
  }
}